// Round 14
// baseline (499.977 us; speedup 1.0000x reference)
//
#include <hip/hip_runtime.h>

#define TPB 128  // 2 waves share one 64-row mT; wave wv owns q-half wv

typedef _Float16 f16x8 __attribute__((ext_vector_type(8)));
typedef __fp16 h16x2 __attribute__((ext_vector_type(2)));  // cvt_pkrtz native type
typedef float f32x4 __attribute__((ext_vector_type(4)));

// fp16 weight tiles (16x16x32 B-fragment order), tile(n-1, s, t) of 512 f16:
static constexpr int WT_L0 = 0;        // 8n*2s*8t*512 = 65536
static constexpr int WT_L1 = 65536;    // 8n*4s*8t*512 = 131072 each
static constexpr int WT_L2 = 196608;
static constexpr int WT_L3 = 327680;
static constexpr int WT_END = 458752;          // f16 elements per plane (hi, lo)
static constexpr int F32_BASE = WT_END;        // float offset into ws (2 f16 planes)
static constexpr int MST = 132;                // mT row stride (floats)

// ---------- helpers ----------
__device__ __forceinline__ float fast_tanh2(float x) {  // 2*tanh(x)
  float e = __expf(2.0f * x);
  return fmaf(-4.0f, __builtin_amdgcn_rcpf(e + 1.0f), 2.0f);
}
__device__ __forceinline__ float gelu_exact(float v) {
  return 0.5f * v * (1.0f + erff(v * 0.70710678f));
}

// ---------- fusion kernels (verified R8 layout, unchanged) ----------
// within-tile e = lane*8 + j: q = lane&15 (bits 3..6), g = lane>>4 (bits 7..8)
// p = s*32 + g*8 + j ; qg = t*16 + q ; coef n = n1+1
__global__ void fuse_w_f16(const float* __restrict__ W, const float* __restrict__ tW,
                           _Float16* __restrict__ out_hi, _Float16* __restrict__ out_lo,
                           int P, int total, int sbits) {
  int i = blockIdx.x * 256 + threadIdx.x;
  if (i >= total) return;
  int j = i & 7, q = (i >> 3) & 15, g = (i >> 7) & 3, t = (i >> 9) & 7;
  int s = (i >> 12) & ((1 << sbits) - 1);
  int n1 = i >> (12 + sbits);  // n-1 in 0..7
  int p = s * 32 + g * 8 + j;
  int qg = t * 16 + q;
  float v = tW[(qg * P + p) * 9 + (n1 + 1)] * W[qg * P + p];
  _Float16 hi = (_Float16)v;
  out_hi[i] = hi;
  out_lo[i] = (_Float16)(v - (float)hi);
}
__global__ void fuse_bias(const float* __restrict__ W, const float* __restrict__ tW,
                          float* __restrict__ bias, int P, int Q) {
  int q = blockIdx.x * 64 + threadIdx.x;
  if (q >= Q) return;
  float s = 0.0f;
  for (int p = 0; p < P; ++p) s += tW[(q * P + p) * 9] * W[q * P + p];
  bias[q] = s;
}
__global__ void fuse_w4(const float* __restrict__ W, const float* __restrict__ tW,
                        float* __restrict__ out) {
  int i = blockIdx.x * 128 + threadIdx.x;
  if (i >= 1152) return;
  out[i] = tW[i] * W[i / 9];
}

// ---------- layer: wave computes 64 rows (mt=4) x 64 q (qt=4) ----------
// B/MFMA = 170B; lane-local recurrence for 4 row-tiles; no per-chunk barriers.
template <int S, bool RES>
__device__ __forceinline__ void layer44(const float* __restrict__ mT,
                                        const _Float16* __restrict__ wt_hi,
                                        const _Float16* __restrict__ wt_lo,
                                        const float* __restrict__ biasL,
                                        f32x4 (&acc)[4][4], int l, int wv) {
  const int c15 = l & 15, g = l >> 4;
#pragma unroll
  for (int qt = 0; qt < 4; ++qt) {
    float bv = biasL[wv * 64 + qt * 16 + c15];
#pragma unroll
    for (int rt = 0; rt < 4; ++rt)
#pragma unroll
      for (int j = 0; j < 4; ++j) {
        if (RES) acc[rt][qt][j] += bv; else acc[rt][qt][j] = bv;
      }
  }
  const _Float16* bh_base = wt_hi + wv * 2048 + l * 8;  // tiles t = wv*4 .. wv*4+3
  const _Float16* bl_base = wt_lo + wv * 2048 + l * 8;
  float mv[4][8], up[4][8], uc[4][8];
#pragma unroll 1
  for (int k = 0; k < 8 * S; ++k) {
    int s = k >> 3, n1 = k & 7;
    // B loads issued first; recurrence+pack covers latency
    size_t toff = (size_t)(n1 * S + s) * 4096;
    f16x8 bh[4], bl[4];
#pragma unroll
    for (int qt = 0; qt < 4; ++qt) {
      bh[qt] = *(const f16x8*)(bh_base + toff + qt * 512);
      bl[qt] = *(const f16x8*)(bl_base + toff + qt * 512);
    }
    if (n1 == 0) {
#pragma unroll
      for (int rt = 0; rt < 4; ++rt) {
        const f32x4* mp = (const f32x4*)(mT + (rt * 16 + c15) * MST + s * 32 + g * 8);
        f32x4 a = mp[0], b = mp[1];
#pragma unroll
        for (int i = 0; i < 4; ++i) { mv[rt][i] = a[i]; mv[rt][4 + i] = b[i]; }
#pragma unroll
        for (int i = 0; i < 8; ++i) { up[rt][i] = 1.0f; uc[rt][i] = mv[rt][i]; }
      }
    } else {
#pragma unroll
      for (int rt = 0; rt < 4; ++rt)
#pragma unroll
        for (int i = 0; i < 8; ++i) {
          float u = fmaf(mv[rt][i], uc[rt][i], -up[rt][i]);
          up[rt][i] = uc[rt][i];
          uc[rt][i] = u;
        }
    }
    // pack T_{n1+1} -> hi/lo fp16 A-frags
    f16x8 afh[4], afl[4];
#pragma unroll
    for (int rt = 0; rt < 4; ++rt) {
      union UU { h16x2 h2[4]; f16x8 v; } uh, ul;
#pragma unroll
      for (int ii = 0; ii < 4; ++ii) {
        float v0 = uc[rt][2 * ii], v1 = uc[rt][2 * ii + 1];
        h16x2 h = __builtin_amdgcn_cvt_pkrtz(v0, v1);
        uh.h2[ii] = h;
        ul.h2[ii] = __builtin_amdgcn_cvt_pkrtz(v0 - (float)h[0], v1 - (float)h[1]);
      }
      afh[rt] = uh.v;
      afl[rt] = ul.v;
    }
    __builtin_amdgcn_s_setprio(1);
#pragma unroll
    for (int qt = 0; qt < 4; ++qt)
#pragma unroll
      for (int rt = 0; rt < 4; ++rt)
        acc[rt][qt] = __builtin_amdgcn_mfma_f32_16x16x32_f16(afh[rt], bh[qt],
                                                             acc[rt][qt], 0, 0, 0);
#pragma unroll
    for (int qt = 0; qt < 4; ++qt)
#pragma unroll
      for (int rt = 0; rt < 4; ++rt)
        acc[rt][qt] = __builtin_amdgcn_mfma_f32_16x16x32_f16(afl[rt], bh[qt],
                                                             acc[rt][qt], 0, 0, 0);
#pragma unroll
    for (int qt = 0; qt < 4; ++qt)
#pragma unroll
      for (int rt = 0; rt < 4; ++rt)
        acc[rt][qt] = __builtin_amdgcn_mfma_f32_16x16x32_f16(afh[rt], bl[qt],
                                                             acc[rt][qt], 0, 0, 0);
    __builtin_amdgcn_s_setprio(0);
  }
}

// write m = 2tanh(acc) into mT; C-layout: row=rt*16+(l>>4)*4+j, col=wv*64+qt*16+(l&15)
__device__ __forceinline__ void write_m(float* __restrict__ mT,
                                        const f32x4 (&acc)[4][4], int l, int wv) {
  const int c15 = l & 15, g = l >> 4;
#pragma unroll
  for (int rt = 0; rt < 4; ++rt)
#pragma unroll
    for (int qt = 0; qt < 4; ++qt)
#pragma unroll
      for (int j = 0; j < 4; ++j) {
        int row = rt * 16 + g * 4 + j;
        int col = wv * 64 + qt * 16 + c15;
        mT[row * MST + col] = fast_tanh2(acc[rt][qt][j]);
      }
}

// ---------- main kernel ----------
__global__ void __launch_bounds__(TPB, 2)
kan_mfma(const float* __restrict__ x, const float* __restrict__ Bm,
         const _Float16* __restrict__ wt_hi, const _Float16* __restrict__ wt_lo,
         const float* __restrict__ bias, const float* __restrict__ w4,
         float* __restrict__ out) {
  __shared__ float mT[64 * MST];  // 33.8 KB shared by both waves
  __shared__ float xb[64];        // L4 partial exchange
  int tid = threadIdx.x;
  int l = tid & 63;
  int wv = tid >> 6;
  int row0 = blockIdx.x * 64;

  // ---- Fourier features -> mT (thread: row=l, features wv*16..wv*16+15) ----
  {
    const float4* xp = (const float4*)(x + (size_t)(row0 + l) * 8);
    float4 a = xp[0], c4 = xp[1];
    float xv[8] = {a.x, a.y, a.z, a.w, c4.x, c4.y, c4.z, c4.w};
#pragma unroll
    for (int jj = 0; jj < 16; ++jj) {
      int j = wv * 16 + jj;
      float pr = 0.0f;
#pragma unroll
      for (int k = 0; k < 8; ++k) pr = fmaf(xv[k], Bm[k * 32 + j], pr);
      float ang = 6.2831853071795864f * pr;
      float sv, cv;
      sincosf(ang, &sv, &cv);
      mT[l * MST + j] = fast_tanh2(sv);
      mT[l * MST + 32 + j] = fast_tanh2(cv);
    }
  }
  __syncthreads();

  f32x4 acc[4][4];
  layer44<2, false>(mT, wt_hi + WT_L0, wt_lo + WT_L0, bias + 0, acc, l, wv);
  __syncthreads();
  write_m(mT, acc, l, wv);
  __syncthreads();
  layer44<4, true>(mT, wt_hi + WT_L1, wt_lo + WT_L1, bias + 128, acc, l, wv);
  __syncthreads();
  write_m(mT, acc, l, wv);
  __syncthreads();
  layer44<4, true>(mT, wt_hi + WT_L2, wt_lo + WT_L2, bias + 256, acc, l, wv);
  __syncthreads();
  write_m(mT, acc, l, wv);
  __syncthreads();
  layer44<4, true>(mT, wt_hi + WT_L3, wt_lo + WT_L3, bias + 384, acc, l, wv);
  __syncthreads();
  write_m(mT, acc, l, wv);
  __syncthreads();

  // ---- L4: 128 -> 1 (wave wv handles p-half wv for all 64 rows) ----
  {
    const float* w4h = w4 + wv * 64 * 9;
    const float* mrow = mT + l * MST + wv * 64;
    float part = 0.0f;
#pragma unroll 4
    for (int pp = 0; pp < 64; ++pp) {
      float mm = mrow[pp];
      const float* wp = w4h + pp * 9;
      part += wp[0];
      part = fmaf(mm, wp[1], part);
      float u2 = 1.0f, u1 = mm;
#pragma unroll
      for (int n = 2; n < 9; ++n) {
        float u = fmaf(mm, u1, -u2);
        u2 = u1;
        u1 = u;
        part = fmaf(u, wp[n], part);
      }
    }
    if (wv == 1) xb[l] = part;
    __syncthreads();
    if (wv == 0) {
      float v = part + xb[l];
      float t = 0.5f * fast_tanh2(v);
      float m2 = t + t;
      float tm2 = 1.0f, tm1 = t;
      float y = gelu_exact(1.0f) + gelu_exact(t);
#pragma unroll
      for (int n = 2; n <= 5; ++n) {
        float tn = fmaf(m2, tm1, -tm2);
        tm2 = tm1;
        tm1 = tn;
        y += gelu_exact(tn);
      }
      out[row0 + l] = y;
    }
  }
}

extern "C" void kernel_launch(void* const* d_in, const int* in_sizes, int n_in,
                              void* d_out, int out_size, void* d_ws, size_t ws_size,
                              hipStream_t stream) {
  const float* x   = (const float*)d_in[0];
  const float* Bm  = (const float*)d_in[1];
  const float* W0  = (const float*)d_in[2];
  const float* tW0 = (const float*)d_in[3];
  const float* W1  = (const float*)d_in[4];
  const float* tW1 = (const float*)d_in[5];
  const float* W2  = (const float*)d_in[6];
  const float* tW2 = (const float*)d_in[7];
  const float* W3  = (const float*)d_in[8];
  const float* tW3 = (const float*)d_in[9];
  const float* W4  = (const float*)d_in[10];
  const float* tW4 = (const float*)d_in[11];

  _Float16* wt_hi = (_Float16*)d_ws;
  _Float16* wt_lo = wt_hi + WT_END;
  float* fws = (float*)d_ws + F32_BASE;
  float* bias = fws;        // 4*128 floats
  float* w4 = fws + 512;    // 1152 floats

  fuse_w_f16<<<65536 / 256, 256, 0, stream>>>(W0, tW0, wt_hi + WT_L0, wt_lo + WT_L0, 64, 65536, 1);
  fuse_w_f16<<<131072 / 256, 256, 0, stream>>>(W1, tW1, wt_hi + WT_L1, wt_lo + WT_L1, 128, 131072, 2);
  fuse_w_f16<<<131072 / 256, 256, 0, stream>>>(W2, tW2, wt_hi + WT_L2, wt_lo + WT_L2, 128, 131072, 2);
  fuse_w_f16<<<131072 / 256, 256, 0, stream>>>(W3, tW3, wt_hi + WT_L3, wt_lo + WT_L3, 128, 131072, 2);
  fuse_bias<<<2, 64, 0, stream>>>(W0, tW0, bias + 0, 64, 128);
  fuse_bias<<<2, 64, 0, stream>>>(W1, tW1, bias + 128, 128, 128);
  fuse_bias<<<2, 64, 0, stream>>>(W2, tW2, bias + 256, 128, 128);
  fuse_bias<<<2, 64, 0, stream>>>(W3, tW3, bias + 384, 128, 128);
  fuse_w4<<<9, 128, 0, stream>>>(W4, tW4, w4);

  kan_mfma<<<131072 / 64, TPB, 0, stream>>>(x, Bm, wt_hi, wt_lo, bias, w4, (float*)d_out);
}

// Round 15
// 484.480 us; speedup vs baseline: 1.0320x; 1.0320x over previous
//
#include <hip/hip_runtime.h>

#define TPB 128  // 2 waves share one 64-row mT; wave wv owns q-half wv; 1 wave/SIMD

typedef _Float16 f16x8 __attribute__((ext_vector_type(8)));
typedef __fp16 h16x2 __attribute__((ext_vector_type(2)));  // cvt_pkrtz native type
typedef float f32x4 __attribute__((ext_vector_type(4)));

// fp16 weight tiles (16x16x32 B-fragment order), tile(n-1, s, t) of 512 f16:
static constexpr int WT_L0 = 0;        // 8n*2s*8t*512 = 65536
static constexpr int WT_L1 = 65536;    // 8n*4s*8t*512 = 131072 each
static constexpr int WT_L2 = 196608;
static constexpr int WT_L3 = 327680;
static constexpr int WT_END = 458752;          // f16 elements per plane (hi, lo)
static constexpr int F32_BASE = WT_END;        // float offset into ws (2 f16 planes)
static constexpr int MST = 132;                // mT row stride (floats)

// ---------- helpers ----------
__device__ __forceinline__ float fast_tanh2(float x) {  // 2*tanh(x)
  float e = __expf(2.0f * x);
  return fmaf(-4.0f, __builtin_amdgcn_rcpf(e + 1.0f), 2.0f);
}
__device__ __forceinline__ float gelu_exact(float v) {
  return 0.5f * v * (1.0f + erff(v * 0.70710678f));
}

// ---------- fusion kernels (verified R8 layout, unchanged) ----------
// within-tile e = lane*8 + j: q = lane&15 (bits 3..6), g = lane>>4 (bits 7..8)
// p = s*32 + g*8 + j ; qg = t*16 + q ; coef n = n1+1
__global__ void fuse_w_f16(const float* __restrict__ W, const float* __restrict__ tW,
                           _Float16* __restrict__ out_hi, _Float16* __restrict__ out_lo,
                           int P, int total, int sbits) {
  int i = blockIdx.x * 256 + threadIdx.x;
  if (i >= total) return;
  int j = i & 7, q = (i >> 3) & 15, g = (i >> 7) & 3, t = (i >> 9) & 7;
  int s = (i >> 12) & ((1 << sbits) - 1);
  int n1 = i >> (12 + sbits);  // n-1 in 0..7
  int p = s * 32 + g * 8 + j;
  int qg = t * 16 + q;
  float v = tW[(qg * P + p) * 9 + (n1 + 1)] * W[qg * P + p];
  _Float16 hi = (_Float16)v;
  out_hi[i] = hi;
  out_lo[i] = (_Float16)(v - (float)hi);
}
__global__ void fuse_bias(const float* __restrict__ W, const float* __restrict__ tW,
                          float* __restrict__ bias, int P, int Q) {
  int q = blockIdx.x * 64 + threadIdx.x;
  if (q >= Q) return;
  float s = 0.0f;
  for (int p = 0; p < P; ++p) s += tW[(q * P + p) * 9] * W[q * P + p];
  bias[q] = s;
}
__global__ void fuse_w4(const float* __restrict__ W, const float* __restrict__ tW,
                        float* __restrict__ out) {
  int i = blockIdx.x * 128 + threadIdx.x;
  if (i >= 1152) return;
  out[i] = tW[i] * W[i / 9];
}

// ---------- layer: wave computes 64 rows (mt=4) x 64 q (qt=4) ----------
// B/MFMA = 170B -> demand 35 B/cyc/CU at full matrix rate (= measured delivery).
// Single wave per SIMD saturates the matrix pipe (931 cyc/chunk vs ~300 VALU).
template <int S, bool RES>
__device__ __forceinline__ void layer44(const float* __restrict__ mT,
                                        const _Float16* __restrict__ wt_hi,
                                        const _Float16* __restrict__ wt_lo,
                                        const float* __restrict__ biasL,
                                        f32x4 (&acc)[4][4], int l, int wv) {
  const int c15 = l & 15, g = l >> 4;
#pragma unroll
  for (int qt = 0; qt < 4; ++qt) {
    float bv = biasL[wv * 64 + qt * 16 + c15];
#pragma unroll
    for (int rt = 0; rt < 4; ++rt)
#pragma unroll
      for (int j = 0; j < 4; ++j) {
        if (RES) acc[rt][qt][j] += bv; else acc[rt][qt][j] = bv;
      }
  }
  const _Float16* bh_base = wt_hi + wv * 2048 + l * 8;  // tiles t = wv*4 .. wv*4+3
  const _Float16* bl_base = wt_lo + wv * 2048 + l * 8;
  float mv[4][8], up[4][8], uc[4][8];
#pragma unroll 1
  for (int k = 0; k < 8 * S; ++k) {
    int s = k >> 3, n1 = k & 7;
    // B loads issued first; recurrence+pack (~300 cyc) covers L2 latency
    size_t toff = (size_t)(n1 * S + s) * 4096;
    f16x8 bh[4], bl[4];
#pragma unroll
    for (int qt = 0; qt < 4; ++qt) {
      bh[qt] = *(const f16x8*)(bh_base + toff + qt * 512);
      bl[qt] = *(const f16x8*)(bl_base + toff + qt * 512);
    }
    if (n1 == 0) {
#pragma unroll
      for (int rt = 0; rt < 4; ++rt) {
        const f32x4* mp = (const f32x4*)(mT + (rt * 16 + c15) * MST + s * 32 + g * 8);
        f32x4 a = mp[0], b = mp[1];
#pragma unroll
        for (int i = 0; i < 4; ++i) { mv[rt][i] = a[i]; mv[rt][4 + i] = b[i]; }
#pragma unroll
        for (int i = 0; i < 8; ++i) { up[rt][i] = 1.0f; uc[rt][i] = mv[rt][i]; }
      }
    } else {
#pragma unroll
      for (int rt = 0; rt < 4; ++rt)
#pragma unroll
        for (int i = 0; i < 8; ++i) {
          float u = fmaf(mv[rt][i], uc[rt][i], -up[rt][i]);
          up[rt][i] = uc[rt][i];
          uc[rt][i] = u;
        }
    }
    // pack T_{n1+1} -> hi/lo fp16 A-frags
    f16x8 afh[4], afl[4];
#pragma unroll
    for (int rt = 0; rt < 4; ++rt) {
      union UU { h16x2 h2[4]; f16x8 v; } uh, ul;
#pragma unroll
      for (int ii = 0; ii < 4; ++ii) {
        float v0 = uc[rt][2 * ii], v1 = uc[rt][2 * ii + 1];
        h16x2 h = __builtin_amdgcn_cvt_pkrtz(v0, v1);
        uh.h2[ii] = h;
        ul.h2[ii] = __builtin_amdgcn_cvt_pkrtz(v0 - (float)h[0], v1 - (float)h[1]);
      }
      afh[rt] = uh.v;
      afl[rt] = ul.v;
    }
    __builtin_amdgcn_s_setprio(1);
#pragma unroll
    for (int qt = 0; qt < 4; ++qt)
#pragma unroll
      for (int rt = 0; rt < 4; ++rt)
        acc[rt][qt] = __builtin_amdgcn_mfma_f32_16x16x32_f16(afh[rt], bh[qt],
                                                             acc[rt][qt], 0, 0, 0);
#pragma unroll
    for (int qt = 0; qt < 4; ++qt)
#pragma unroll
      for (int rt = 0; rt < 4; ++rt)
        acc[rt][qt] = __builtin_amdgcn_mfma_f32_16x16x32_f16(afl[rt], bh[qt],
                                                             acc[rt][qt], 0, 0, 0);
#pragma unroll
    for (int qt = 0; qt < 4; ++qt)
#pragma unroll
      for (int rt = 0; rt < 4; ++rt)
        acc[rt][qt] = __builtin_amdgcn_mfma_f32_16x16x32_f16(afh[rt], bl[qt],
                                                             acc[rt][qt], 0, 0, 0);
    __builtin_amdgcn_s_setprio(0);
  }
}

// write m = 2tanh(acc) into mT; C-layout: row=rt*16+(l>>4)*4+j, col=wv*64+qt*16+(l&15)
__device__ __forceinline__ void write_m(float* __restrict__ mT,
                                        const f32x4 (&acc)[4][4], int l, int wv) {
  const int c15 = l & 15, g = l >> 4;
#pragma unroll
  for (int rt = 0; rt < 4; ++rt)
#pragma unroll
    for (int qt = 0; qt < 4; ++qt)
#pragma unroll
      for (int j = 0; j < 4; ++j) {
        int row = rt * 16 + g * 4 + j;
        int col = wv * 64 + qt * 16 + c15;
        mT[row * MST + col] = fast_tanh2(acc[rt][qt][j]);
      }
}

// ---------- main kernel ----------
__global__ void __launch_bounds__(TPB, 1)  // 512-reg budget: no spill (R14 lesson)
kan_mfma(const float* __restrict__ x, const float* __restrict__ Bm,
         const _Float16* __restrict__ wt_hi, const _Float16* __restrict__ wt_lo,
         const float* __restrict__ bias, const float* __restrict__ w4,
         float* __restrict__ out) {
  __shared__ float mT[64 * MST];  // 33.8 KB shared by both waves
  __shared__ float xb[64];        // L4 partial exchange
  int tid = threadIdx.x;
  int l = tid & 63;
  int wv = tid >> 6;
  int row0 = blockIdx.x * 64;

  // ---- Fourier features -> mT (thread: row=l, features wv*16..wv*16+15) ----
  {
    const float4* xp = (const float4*)(x + (size_t)(row0 + l) * 8);
    float4 a = xp[0], c4 = xp[1];
    float xv[8] = {a.x, a.y, a.z, a.w, c4.x, c4.y, c4.z, c4.w};
#pragma unroll
    for (int jj = 0; jj < 16; ++jj) {
      int j = wv * 16 + jj;
      float pr = 0.0f;
#pragma unroll
      for (int k = 0; k < 8; ++k) pr = fmaf(xv[k], Bm[k * 32 + j], pr);
      float ang = 6.2831853071795864f * pr;
      float sv, cv;
      sincosf(ang, &sv, &cv);
      mT[l * MST + j] = fast_tanh2(sv);
      mT[l * MST + 32 + j] = fast_tanh2(cv);
    }
  }
  __syncthreads();

  f32x4 acc[4][4];
  layer44<2, false>(mT, wt_hi + WT_L0, wt_lo + WT_L0, bias + 0, acc, l, wv);
  __syncthreads();
  write_m(mT, acc, l, wv);
  __syncthreads();
  layer44<4, true>(mT, wt_hi + WT_L1, wt_lo + WT_L1, bias + 128, acc, l, wv);
  __syncthreads();
  write_m(mT, acc, l, wv);
  __syncthreads();
  layer44<4, true>(mT, wt_hi + WT_L2, wt_lo + WT_L2, bias + 256, acc, l, wv);
  __syncthreads();
  write_m(mT, acc, l, wv);
  __syncthreads();
  layer44<4, true>(mT, wt_hi + WT_L3, wt_lo + WT_L3, bias + 384, acc, l, wv);
  __syncthreads();
  write_m(mT, acc, l, wv);
  __syncthreads();

  // ---- L4: 128 -> 1 (wave wv handles p-half wv for all 64 rows) ----
  {
    const float* w4h = w4 + wv * 64 * 9;
    const float* mrow = mT + l * MST + wv * 64;
    float part = 0.0f;
#pragma unroll 4
    for (int pp = 0; pp < 64; ++pp) {
      float mm = mrow[pp];
      const float* wp = w4h + pp * 9;
      part += wp[0];
      part = fmaf(mm, wp[1], part);
      float u2 = 1.0f, u1 = mm;
#pragma unroll
      for (int n = 2; n < 9; ++n) {
        float u = fmaf(mm, u1, -u2);
        u2 = u1;
        u1 = u;
        part = fmaf(u, wp[n], part);
      }
    }
    if (wv == 1) xb[l] = part;
    __syncthreads();
    if (wv == 0) {
      float v = part + xb[l];
      float t = 0.5f * fast_tanh2(v);
      float m2 = t + t;
      float tm2 = 1.0f, tm1 = t;
      float y = gelu_exact(1.0f) + gelu_exact(t);
#pragma unroll
      for (int n = 2; n <= 5; ++n) {
        float tn = fmaf(m2, tm1, -tm2);
        tm2 = tm1;
        tm1 = tn;
        y += gelu_exact(tn);
      }
      out[row0 + l] = y;
    }
  }
}

extern "C" void kernel_launch(void* const* d_in, const int* in_sizes, int n_in,
                              void* d_out, int out_size, void* d_ws, size_t ws_size,
                              hipStream_t stream) {
  const float* x   = (const float*)d_in[0];
  const float* Bm  = (const float*)d_in[1];
  const float* W0  = (const float*)d_in[2];
  const float* tW0 = (const float*)d_in[3];
  const float* W1  = (const float*)d_in[4];
  const float* tW1 = (const float*)d_in[5];
  const float* W2  = (const float*)d_in[6];
  const float* tW2 = (const float*)d_in[7];
  const float* W3  = (const float*)d_in[8];
  const float* tW3 = (const float*)d_in[9];
  const float* W4  = (const float*)d_in[10];
  const float* tW4 = (const float*)d_in[11];

  _Float16* wt_hi = (_Float16*)d_ws;
  _Float16* wt_lo = wt_hi + WT_END;
  float* fws = (float*)d_ws + F32_BASE;
  float* bias = fws;        // 4*128 floats
  float* w4 = fws + 512;    // 1152 floats

  fuse_w_f16<<<65536 / 256, 256, 0, stream>>>(W0, tW0, wt_hi + WT_L0, wt_lo + WT_L0, 64, 65536, 1);
  fuse_w_f16<<<131072 / 256, 256, 0, stream>>>(W1, tW1, wt_hi + WT_L1, wt_lo + WT_L1, 128, 131072, 2);
  fuse_w_f16<<<131072 / 256, 256, 0, stream>>>(W2, tW2, wt_hi + WT_L2, wt_lo + WT_L2, 128, 131072, 2);
  fuse_w_f16<<<131072 / 256, 256, 0, stream>>>(W3, tW3, wt_hi + WT_L3, wt_lo + WT_L3, 128, 131072, 2);
  fuse_bias<<<2, 64, 0, stream>>>(W0, tW0, bias + 0, 64, 128);
  fuse_bias<<<2, 64, 0, stream>>>(W1, tW1, bias + 128, 128, 128);
  fuse_bias<<<2, 64, 0, stream>>>(W2, tW2, bias + 256, 128, 128);
  fuse_bias<<<2, 64, 0, stream>>>(W3, tW3, bias + 384, 128, 128);
  fuse_w4<<<9, 128, 0, stream>>>(W4, tW4, w4);

  kan_mfma<<<131072 / 64, TPB, 0, stream>>>(x, Bm, wt_hi, wt_lo, bias, w4, (float*)d_out);
}

// Round 16
// 450.086 us; speedup vs baseline: 1.1108x; 1.0764x over previous
//
#include <hip/hip_runtime.h>

#define TPB 256  // 4 waves; wave wv: all 64 rows (mt=4) x q-quarter (qt=2)

typedef _Float16 f16x8 __attribute__((ext_vector_type(8)));
typedef __fp16 h16x2 __attribute__((ext_vector_type(2)));  // cvt_pkrtz native type
typedef float f32x4 __attribute__((ext_vector_type(4)));

// fp16 weight tiles (16x16x32 B-fragment order), tile(n-1, s, t) of 512 f16:
static constexpr int WT_L0 = 0;        // 8n*2s*8t*512 = 65536
static constexpr int WT_L1 = 65536;    // 8n*4s*8t*512 = 131072 each
static constexpr int WT_L2 = 196608;
static constexpr int WT_L3 = 327680;
static constexpr int WT_END = 458752;          // f16 elements per plane (hi, lo)
static constexpr int F32_BASE = WT_END;        // float offset into ws (2 f16 planes)
static constexpr int MST = 132;                // mT row stride (floats)

// ---------- helpers ----------
__device__ __forceinline__ float fast_tanh2(float x) {  // 2*tanh(x)
  float e = __expf(2.0f * x);
  return fmaf(-4.0f, __builtin_amdgcn_rcpf(e + 1.0f), 2.0f);
}
__device__ __forceinline__ float gelu_exact(float v) {
  return 0.5f * v * (1.0f + erff(v * 0.70710678f));
}

// ---------- fusion kernels (verified R8 layout, unchanged) ----------
__global__ void fuse_w_f16(const float* __restrict__ W, const float* __restrict__ tW,
                           _Float16* __restrict__ out_hi, _Float16* __restrict__ out_lo,
                           int P, int total, int sbits) {
  int i = blockIdx.x * 256 + threadIdx.x;
  if (i >= total) return;
  int j = i & 7, q = (i >> 3) & 15, g = (i >> 7) & 3, t = (i >> 9) & 7;
  int s = (i >> 12) & ((1 << sbits) - 1);
  int n1 = i >> (12 + sbits);  // n-1 in 0..7
  int p = s * 32 + g * 8 + j;
  int qg = t * 16 + q;
  float v = tW[(qg * P + p) * 9 + (n1 + 1)] * W[qg * P + p];
  _Float16 hi = (_Float16)v;
  out_hi[i] = hi;
  out_lo[i] = (_Float16)(v - (float)hi);
}
__global__ void fuse_bias(const float* __restrict__ W, const float* __restrict__ tW,
                          float* __restrict__ bias, int P, int Q) {
  int q = blockIdx.x * 64 + threadIdx.x;
  if (q >= Q) return;
  float s = 0.0f;
  for (int p = 0; p < P; ++p) s += tW[(q * P + p) * 9] * W[q * P + p];
  bias[q] = s;
}
__global__ void fuse_w4(const float* __restrict__ W, const float* __restrict__ tW,
                        float* __restrict__ out) {
  int i = blockIdx.x * 128 + threadIdx.x;
  if (i >= 1152) return;
  out[i] = tW[i] * W[i / 9];
}

// ---------- layer: wave = 64 rows (mt=4) x 32 q (qt=2); B double-buffered ----------
template <int S, bool RES>
__device__ __forceinline__ void layer42(const float* __restrict__ mT,
                                        const _Float16* __restrict__ wt_hi,
                                        const _Float16* __restrict__ wt_lo,
                                        const float* __restrict__ biasL,
                                        f32x4 (&acc)[4][2], int l, int wv) {
  const int c15 = l & 15, g = l >> 4;
#pragma unroll
  for (int qt = 0; qt < 2; ++qt) {
    float bv = biasL[wv * 32 + qt * 16 + c15];
#pragma unroll
    for (int rt = 0; rt < 4; ++rt)
#pragma unroll
      for (int j = 0; j < 4; ++j) {
        if (RES) acc[rt][qt][j] += bv; else acc[rt][qt][j] = bv;
      }
  }
  const _Float16* bh_base = wt_hi + wv * 1024 + l * 8;  // tiles t = wv*2, wv*2+1
  const _Float16* bl_base = wt_lo + wv * 1024 + l * 8;
  float mv[4][8], up[4][8], uc[4][8];
  f16x8 b0h[2], b0l[2], b1h[2], b1l[2];
  f16x8 afh[4], afl[4];

#define LB(dh, dl, kk)                                                        \
  {                                                                           \
    size_t off_ = (size_t)(((kk) & 7) * S + ((kk) >> 3)) * 4096;              \
    dh[0] = *(const f16x8*)(bh_base + off_);                                  \
    dh[1] = *(const f16x8*)(bh_base + off_ + 512);                            \
    dl[0] = *(const f16x8*)(bl_base + off_);                                  \
    dl[1] = *(const f16x8*)(bl_base + off_ + 512);                            \
  }

#define INITA(s_)                                                             \
  _Pragma("unroll") for (int rt = 0; rt < 4; ++rt) {                          \
    const f32x4* mp_ =                                                        \
        (const f32x4*)(mT + (rt * 16 + c15) * MST + (s_) * 32 + g * 8);       \
    f32x4 a_ = mp_[0], b_ = mp_[1];                                           \
    _Pragma("unroll") for (int ii = 0; ii < 4; ++ii) {                        \
      mv[rt][ii] = a_[ii]; mv[rt][4 + ii] = b_[ii];                           \
    }                                                                         \
    _Pragma("unroll") for (int ii = 0; ii < 8; ++ii) {                        \
      up[rt][ii] = 1.0f; uc[rt][ii] = mv[rt][ii];                             \
    }                                                                         \
  }

#define STEPA()                                                               \
  _Pragma("unroll") for (int rt = 0; rt < 4; ++rt)                            \
    _Pragma("unroll") for (int ii = 0; ii < 8; ++ii) {                        \
      float u_ = fmaf(mv[rt][ii], uc[rt][ii], -up[rt][ii]);                   \
      up[rt][ii] = uc[rt][ii]; uc[rt][ii] = u_;                               \
    }

// pack T_n -> hi (RTZ) + lo; lo via v_fma_mixlo/hi_f16: cvt_f16(v - hi) in 1 inst
#define PACKA()                                                               \
  _Pragma("unroll") for (int rt = 0; rt < 4; ++rt) {                          \
    union AF { unsigned u[4]; f16x8 v; } ah_, al_;                            \
    _Pragma("unroll") for (int ii = 0; ii < 4; ++ii) {                        \
      float v0 = uc[rt][2 * ii], v1 = uc[rt][2 * ii + 1];                     \
      h16x2 h_ = __builtin_amdgcn_cvt_pkrtz(v0, v1);                          \
      unsigned hu_ = *(unsigned*)&h_;                                         \
      unsigned lu_;                                                           \
      asm("v_fma_mixlo_f16 %0, %1, 1.0, -%3 op_sel:[0,0,0] op_sel_hi:[0,0,1]\n\t" \
          "v_fma_mixhi_f16 %0, %2, 1.0, -%3 op_sel:[0,0,1] op_sel_hi:[0,0,1]" \
          : "=&v"(lu_) : "v"(v0), "v"(v1), "v"(hu_));                         \
      ah_.u[ii] = hu_; al_.u[ii] = lu_;                                       \
    }                                                                         \
    afh[rt] = ah_.v; afl[rt] = al_.v;                                         \
  }

#define MFMA24(bh, bl)                                                        \
  {                                                                           \
    __builtin_amdgcn_s_setprio(1);                                            \
    _Pragma("unroll") for (int qt = 0; qt < 2; ++qt)                          \
      _Pragma("unroll") for (int rt = 0; rt < 4; ++rt)                        \
        acc[rt][qt] = __builtin_amdgcn_mfma_f32_16x16x32_f16(                 \
            afh[rt], bh[qt], acc[rt][qt], 0, 0, 0);                           \
    _Pragma("unroll") for (int qt = 0; qt < 2; ++qt)                          \
      _Pragma("unroll") for (int rt = 0; rt < 4; ++rt)                        \
        acc[rt][qt] = __builtin_amdgcn_mfma_f32_16x16x32_f16(                 \
            afl[rt], bh[qt], acc[rt][qt], 0, 0, 0);                           \
    _Pragma("unroll") for (int qt = 0; qt < 2; ++qt)                          \
      _Pragma("unroll") for (int rt = 0; rt < 4; ++rt)                        \
        acc[rt][qt] = __builtin_amdgcn_mfma_f32_16x16x32_f16(                 \
            afh[rt], bl[qt], acc[rt][qt], 0, 0, 0);                           \
    __builtin_amdgcn_s_setprio(0);                                            \
  }

  LB(b0h, b0l, 0);
#pragma unroll 1
  for (int i = 0; i < 4 * S; ++i) {
    int k = 2 * i;
    // chunk k (even): B for k+1 prefetches under this chunk's VALU+MFMA
    LB(b1h, b1l, k + 1);
    if ((k & 7) == 0) { INITA(k >> 3) } else { STEPA() }
    PACKA()
    MFMA24(b0h, b0l)
    // chunk k+1 (odd: always a recurrence step)
    if (k + 2 < 8 * S) LB(b0h, b0l, k + 2);
    STEPA()
    PACKA()
    MFMA24(b1h, b1l)
  }
#undef LB
#undef INITA
#undef STEPA
#undef PACKA
#undef MFMA24
}

// write m = 2tanh(acc) into mT; C-layout: row=rt*16+(l>>4)*4+j, col=wv*32+qt*16+(l&15)
__device__ __forceinline__ void write_m(float* __restrict__ mT,
                                        const f32x4 (&acc)[4][2], int l, int wv) {
  const int c15 = l & 15, g = l >> 4;
#pragma unroll
  for (int rt = 0; rt < 4; ++rt)
#pragma unroll
    for (int qt = 0; qt < 2; ++qt)
#pragma unroll
      for (int j = 0; j < 4; ++j) {
        int row = rt * 16 + g * 4 + j;
        int col = wv * 32 + qt * 16 + c15;
        mT[row * MST + col] = fast_tanh2(acc[rt][qt][j]);
      }
}

// ---------- main kernel ----------
__global__ void __launch_bounds__(TPB, 2)
kan_mfma(const float* __restrict__ x, const float* __restrict__ Bm,
         const _Float16* __restrict__ wt_hi, const _Float16* __restrict__ wt_lo,
         const float* __restrict__ bias, const float* __restrict__ w4,
         float* __restrict__ out) {
  __shared__ float mT[64 * MST];  // 33.8 KB shared by 4 waves
  int tid = threadIdx.x;
  int l = tid & 63;
  int wv = tid >> 6;
  int row0 = blockIdx.x * 64;

  // ---- Fourier features -> mT (thread: row=l, features wv*8..wv*8+7) ----
  {
    const float4* xp = (const float4*)(x + (size_t)(row0 + l) * 8);
    float4 a = xp[0], c4 = xp[1];
    float xv[8] = {a.x, a.y, a.z, a.w, c4.x, c4.y, c4.z, c4.w};
#pragma unroll
    for (int jj = 0; jj < 8; ++jj) {
      int j = wv * 8 + jj;
      float pr = 0.0f;
#pragma unroll
      for (int k = 0; k < 8; ++k) pr = fmaf(xv[k], Bm[k * 32 + j], pr);
      float ang = 6.2831853071795864f * pr;
      float sv, cv;
      sincosf(ang, &sv, &cv);
      mT[l * MST + j] = fast_tanh2(sv);
      mT[l * MST + 32 + j] = fast_tanh2(cv);
    }
  }
  __syncthreads();

  f32x4 acc[4][2];
  layer42<2, false>(mT, wt_hi + WT_L0, wt_lo + WT_L0, bias + 0, acc, l, wv);
  __syncthreads();
  write_m(mT, acc, l, wv);
  __syncthreads();
  layer42<4, true>(mT, wt_hi + WT_L1, wt_lo + WT_L1, bias + 128, acc, l, wv);
  __syncthreads();
  write_m(mT, acc, l, wv);
  __syncthreads();
  layer42<4, true>(mT, wt_hi + WT_L2, wt_lo + WT_L2, bias + 256, acc, l, wv);
  __syncthreads();
  write_m(mT, acc, l, wv);
  __syncthreads();
  layer42<4, true>(mT, wt_hi + WT_L3, wt_lo + WT_L3, bias + 384, acc, l, wv);
  __syncthreads();
  write_m(mT, acc, l, wv);
  __syncthreads();

  // ---- L4: 128 -> 1 (wave wv: rows wv*16..+15; 4 lane-groups split p) ----
  {
    int r16 = l & 15, pq = l >> 4;
    int r = wv * 16 + r16;
    const float* w4h = w4 + pq * 32 * 9;
    float part = 0.0f;
#pragma unroll 4
    for (int pp = 0; pp < 32; ++pp) {
      float mm = mT[r * MST + pq * 32 + pp];
      const float* wp = w4h + pp * 9;
      part += wp[0];
      part = fmaf(mm, wp[1], part);
      float u2 = 1.0f, u1 = mm;
#pragma unroll
      for (int n = 2; n < 9; ++n) {
        float u = fmaf(mm, u1, -u2);
        u2 = u1;
        u1 = u;
        part = fmaf(u, wp[n], part);
      }
    }
    part += __shfl_xor(part, 16);
    part += __shfl_xor(part, 32);
    if (l < 16) {
      float v = part;
      float t = 0.5f * fast_tanh2(v);
      float m2 = t + t;
      float tm2 = 1.0f, tm1 = t;
      float y = gelu_exact(1.0f) + gelu_exact(t);
#pragma unroll
      for (int n = 2; n <= 5; ++n) {
        float tn = fmaf(m2, tm1, -tm2);
        tm2 = tm1;
        tm1 = tn;
        y += gelu_exact(tn);
      }
      out[row0 + r] = y;
    }
  }
}

extern "C" void kernel_launch(void* const* d_in, const int* in_sizes, int n_in,
                              void* d_out, int out_size, void* d_ws, size_t ws_size,
                              hipStream_t stream) {
  const float* x   = (const float*)d_in[0];
  const float* Bm  = (const float*)d_in[1];
  const float* W0  = (const float*)d_in[2];
  const float* tW0 = (const float*)d_in[3];
  const float* W1  = (const float*)d_in[4];
  const float* tW1 = (const float*)d_in[5];
  const float* W2  = (const float*)d_in[6];
  const float* tW2 = (const float*)d_in[7];
  const float* W3  = (const float*)d_in[8];
  const float* tW3 = (const float*)d_in[9];
  const float* W4  = (const float*)d_in[10];
  const float* tW4 = (const float*)d_in[11];

  _Float16* wt_hi = (_Float16*)d_ws;
  _Float16* wt_lo = wt_hi + WT_END;
  float* fws = (float*)d_ws + F32_BASE;
  float* bias = fws;        // 4*128 floats
  float* w4 = fws + 512;    // 1152 floats

  fuse_w_f16<<<65536 / 256, 256, 0, stream>>>(W0, tW0, wt_hi + WT_L0, wt_lo + WT_L0, 64, 65536, 1);
  fuse_w_f16<<<131072 / 256, 256, 0, stream>>>(W1, tW1, wt_hi + WT_L1, wt_lo + WT_L1, 128, 131072, 2);
  fuse_w_f16<<<131072 / 256, 256, 0, stream>>>(W2, tW2, wt_hi + WT_L2, wt_lo + WT_L2, 128, 131072, 2);
  fuse_w_f16<<<131072 / 256, 256, 0, stream>>>(W3, tW3, wt_hi + WT_L3, wt_lo + WT_L3, 128, 131072, 2);
  fuse_bias<<<2, 64, 0, stream>>>(W0, tW0, bias + 0, 64, 128);
  fuse_bias<<<2, 64, 0, stream>>>(W1, tW1, bias + 128, 128, 128);
  fuse_bias<<<2, 64, 0, stream>>>(W2, tW2, bias + 256, 128, 128);
  fuse_bias<<<2, 64, 0, stream>>>(W3, tW3, bias + 384, 128, 128);
  fuse_w4<<<9, 128, 0, stream>>>(W4, tW4, w4);

  kan_mfma<<<131072 / 64, TPB, 0, stream>>>(x, Bm, wt_hi, wt_lo, bias, w4, (float*)d_out);
}